// Round 3
// baseline (19.852 us; speedup 1.0000x reference)
//
#include <hip/hip_runtime.h>
#include <math.h>

#define SEQ 2048
#define DIME 128
#define BQ 8
#define NEG_INF -1.0e9f

typedef __attribute__((ext_vector_type(8))) short bf16x8;
typedef __attribute__((ext_vector_type(4))) float f32x4;

// f32 -> bf16 (round-nearest-even)
static __device__ __forceinline__ short f2b(float x) {
  union { float f; unsigned u; } v; v.f = x;
  unsigned r = v.u + 0x7FFF + ((v.u >> 16) & 1);
  return (short)(r >> 16);
}

__global__ __launch_bounds__(512, 4) void swa_kernel(
    const float* __restrict__ q, const float* __restrict__ k,
    const float* __restrict__ v, float* __restrict__ out) {
  // P stride 17 words: PV read banks = (8g + 17j + col)%32 -> max 2-way (free)
  __shared__ float P[160][17];
  __shared__ float mW[9][16];
  __shared__ float sW[9][16];
  __shared__ __attribute__((aligned(16))) float Sinv[16];

  const int tid = threadIdx.x;
  const int lane = tid & 63;
  const int w = tid >> 6;      // wave 0..7
  const int col = lane & 15;
  const int g = lane >> 4;

  const int blk = blockIdx.x;  // 512 blocks: 256 q-tiles x 2 batches
  const int b = blk >> 8;
  const int qs = (blk & 255) * BQ;
  const int kbase = qs - 128;  // window slot 0 -> global key index

  const float* __restrict__ qb = q + (size_t)b * SEQ * DIME;
  const float* __restrict__ kb = k + (size_t)b * SEQ * DIME;
  const float* __restrict__ vb = v + (size_t)b * SEQ * DIME;

  // ---- V prefetch into registers (issued first; latency hides under S phase)
  // wave w owns output dims [16w, 16w+16); B-fragment slot (g,j) <- key 32c+8g+j
  float bvf[5][8];
#pragma unroll
  for (int c = 0; c < 5; ++c)
#pragma unroll
    for (int j = 0; j < 8; ++j) {
      int kg = kbase + 32 * c + 8 * g + j;
      kg = kg < 0 ? 0 : (kg > SEQ - 1 ? SEQ - 1 : kg);
      bvf[c][j] = vb[(size_t)kg * DIME + 16 * w + col];
    }

  // ---- Q fragments (B operand): lane holds Q[qs+col][32kc + 8g + j]
  bf16x8 qf[4];
  {
    int qr = qs + col; qr = qr > SEQ - 1 ? SEQ - 1 : qr;  // cols>=BQ masked later
    const float* qrow = qb + (size_t)qr * DIME + 8 * g;
#pragma unroll
    for (int kc = 0; kc < 4; ++kc) {
      float4 lo = *(const float4*)(qrow + 32 * kc);
      float4 hi = *(const float4*)(qrow + 32 * kc + 4);
      bf16x8 f;
      f[0] = f2b(lo.x); f[1] = f2b(lo.y); f[2] = f2b(lo.z); f[3] = f2b(lo.w);
      f[4] = f2b(hi.x); f[5] = f2b(hi.y); f[6] = f2b(hi.z); f[7] = f2b(hi.w);
      qf[kc] = f;
    }
  }

  // ---- S phase: wave w computes key-tile t=w (wave 7 also t=8).
  // S^T C-layout: row = key_local = 16t+4g+r, col = query (verified r2).
  const float scale = 0.08838834764831845f;  // 128^-0.5
  const int ntile = (w == 7) ? 2 : 1;
  for (int ti = 0; ti < ntile; ++ti) {
    const int t = (ti == 0) ? w : 8;
    f32x4 acc = {0.f, 0.f, 0.f, 0.f};
    int krow = kbase + 16 * t + col;
    krow = krow < 0 ? 0 : (krow > SEQ - 1 ? SEQ - 1 : krow);
    const float* krp = kb + (size_t)krow * DIME + 8 * g;
#pragma unroll
    for (int kc = 0; kc < 4; ++kc) {
      float4 lo = *(const float4*)(krp + 32 * kc);
      float4 hi = *(const float4*)(krp + 32 * kc + 4);
      bf16x8 a;
      a[0] = f2b(lo.x); a[1] = f2b(lo.y); a[2] = f2b(lo.z); a[3] = f2b(lo.w);
      a[4] = f2b(hi.x); a[5] = f2b(hi.y); a[6] = f2b(hi.z); a[7] = f2b(hi.w);
      acc = __builtin_amdgcn_mfma_f32_16x16x32_bf16(a, qf[kc], acc, 0, 0, 0);
    }
    float sc[4];
    float m = NEG_INF;
#pragma unroll
    for (int r = 0; r < 4; ++r) {
      const int kg = kbase + 16 * t + 4 * g + r;
      const int qg = qs + col;
      const bool valid = (col < BQ) && (kg >= 0) && (kg >= qg - 128) && (kg <= qg);
      sc[r] = valid ? acc[r] * scale : NEG_INF;
      m = fmaxf(m, sc[r]);
    }
    // per-tile, per-query max/sum (reduce over g: lanes col, col+16, col+32, col+48)
    m = fmaxf(m, __shfl_xor(m, 16));
    m = fmaxf(m, __shfl_xor(m, 32));
    float s = 0.f;
#pragma unroll
    for (int r = 0; r < 4; ++r) { sc[r] = __expf(sc[r] - m); s += sc[r]; }
    s += __shfl_xor(s, 16);
    s += __shfl_xor(s, 32);
    if (g == 0) { mW[t][col] = m; sW[t][col] = s; }
#pragma unroll
    for (int r = 0; r < 4; ++r) P[16 * t + 4 * g + r][col] = sc[r];
  }

  __syncthreads();

  // ---- global softmax combine: rescale P to common max, build 1/Sum
  {
    const int qq = tid & 15;
    const int ks = tid >> 4;  // 0..31
    float M = mW[0][qq];
#pragma unroll
    for (int t = 1; t < 9; ++t) M = fmaxf(M, mW[t][qq]);
    if (ks == 0) {
      float St = 0.f;
#pragma unroll
      for (int t = 0; t < 9; ++t) St += sW[t][qq] * __expf(mW[t][qq] - M);
      Sinv[qq] = 1.0f / St;
    }
#pragma unroll
    for (int i = 0; i < 5; ++i) {
      const int key = ks + 32 * i;
      if (key < 144) P[key][qq] *= __expf(mW[key >> 4][qq] - M);
      else           P[key][qq] = 0.f;  // pad keys 144..159 for chunk 4
    }
  }

  __syncthreads();

  // ---- PV, dim-split: wave w owns dims [16w,16w+16); contract 160 key-slots
  f32x4 o = {0.f, 0.f, 0.f, 0.f};
#pragma unroll
  for (int c = 0; c < 5; ++c) {
    bf16x8 pa, bv;
#pragma unroll
    for (int j = 0; j < 8; ++j) {
      pa[j] = f2b(P[32 * c + 8 * g + j][col]);  // A: row=q(col), k-slot=key
      bv[j] = f2b(bvf[c][j]);                   // B: k-slot=key, col=dim
    }
    o = __builtin_amdgcn_mfma_f32_16x16x32_bf16(pa, bv, o, 0, 0, 0);
  }

  // O C-layout: lane holds O[q = 4g+r][16w + col]; rows >= BQ are garbage (dropped)
  const f32x4 sv = *(const f32x4*)&Sinv[4 * g];
#pragma unroll
  for (int r = 0; r < 4; ++r) {
    const int qrow = 4 * g + r;
    if (qrow < BQ)
      out[(size_t)(b * SEQ + qs + qrow) * DIME + 16 * w + col] = o[r] * sv[r];
  }
}

extern "C" void kernel_launch(void* const* d_in, const int* in_sizes, int n_in,
                              void* d_out, int out_size, void* d_ws, size_t ws_size,
                              hipStream_t stream) {
  const float* q = (const float*)d_in[0];
  const float* k = (const float*)d_in[1];
  const float* v = (const float*)d_in[2];
  float* out = (float*)d_out;
  // 2 batches x 256 q-tiles of 8 queries = 512 blocks, 8 waves each
  dim3 grid(512), block(512);
  swa_kernel<<<grid, block, 0, stream>>>(q, k, v, out);
}

// Round 4
// 13.343 us; speedup vs baseline: 1.4878x; 1.4878x over previous
//
#include <hip/hip_runtime.h>
#include <math.h>

#define SEQ 2048
#define DIME 128
#define BQ 16
#define NEG_INF -1.0e9f

typedef __attribute__((ext_vector_type(8))) short bf16x8;
typedef __attribute__((ext_vector_type(4))) float f32x4;

// f32 -> bf16 (round-nearest-even)
static __device__ __forceinline__ short f2b(float x) {
  union { float f; unsigned u; } v; v.f = x;
  unsigned r = v.u + 0x7FFF + ((v.u >> 16) & 1);
  return (short)(r >> 16);
}

static __device__ __forceinline__ bf16x8 pack8(const float4 lo, const float4 hi) {
  bf16x8 f;
  f[0] = f2b(lo.x); f[1] = f2b(lo.y); f[2] = f2b(lo.z); f[3] = f2b(lo.w);
  f[4] = f2b(hi.x); f[5] = f2b(hi.y); f[6] = f2b(hi.z); f[7] = f2b(hi.w);
  return f;
}

__global__ __launch_bounds__(256) void swa_kernel(
    const float* __restrict__ q, const float* __restrict__ k,
    const float* __restrict__ v, float* __restrict__ out) {
  // stride 18: PV reads (rows 8g+j) and S writes (rows 4g+r) both <=2-way (free)
  __shared__ float P[160][18];
  __shared__ float mW[9][16];
  __shared__ float sW[9][16];
  __shared__ float scaleW[10][16];   // row 9 = zero pad for key slots 144..159

  const int tid = threadIdx.x;
  const int lane = tid & 63;
  const int w = tid >> 6;      // wave 0..3
  const int col = lane & 15;
  const int g = lane >> 4;

  const int blk = blockIdx.x;  // 256 blocks: 128 q-tiles x 2 batches
  const int b = blk >> 7;
  const int qs = (blk & 127) * BQ;
  const int kbase = qs - 128;  // window slot 0 -> global key index

  const float* __restrict__ qb = q + (size_t)b * SEQ * DIME;
  const float* __restrict__ kb = k + (size_t)b * SEQ * DIME;
  const float* __restrict__ vb = v + (size_t)b * SEQ * DIME;

  // ---- issue Q loads first ----
  float4 qlo[4], qhi[4];
  {
    const float* qrow = qb + (size_t)(qs + col) * DIME + 8 * g;
#pragma unroll
    for (int kc = 0; kc < 4; ++kc) {
      qlo[kc] = *(const float4*)(qrow + 32 * kc);
      qhi[kc] = *(const float4*)(qrow + 32 * kc + 4);
    }
  }

  // ---- issue K loads (own tiles: {2w, 2w+1}, wave0 also tile 8) ----
  float4 kraw[3][8];
#pragma unroll
  for (int ti = 0; ti < 2; ++ti) {
    const int t = 2 * w + ti;
    int krow = kbase + 16 * t + col;
    krow = krow < 0 ? 0 : krow;
    const float* krp = kb + (size_t)krow * DIME + 8 * g;
#pragma unroll
    for (int kc = 0; kc < 4; ++kc) {
      kraw[ti][2 * kc]     = *(const float4*)(krp + 32 * kc);
      kraw[ti][2 * kc + 1] = *(const float4*)(krp + 32 * kc + 4);
    }
  }
  if (w == 0) {
    int krow = kbase + 16 * 8 + col;   // always >= 0
    const float* krp = kb + (size_t)krow * DIME + 8 * g;
#pragma unroll
    for (int kc = 0; kc < 4; ++kc) {
      kraw[2][2 * kc]     = *(const float4*)(krp + 32 * kc);
      kraw[2][2 * kc + 1] = *(const float4*)(krp + 32 * kc + 4);
    }
  }

  // ---- convert Q (waits only on Q loads; V not yet issued) ----
  bf16x8 qf[4];
#pragma unroll
  for (int kc = 0; kc < 4; ++kc) qf[kc] = pack8(qlo[kc], qhi[kc]);

  // ---- issue V prefetch LAST: wave w owns dims [32w,32w+32), slot(g,j)<-key
  //      MFMA B col n maps to global dim 32w + 2n + {0,1}  -> float2 loads
  float2 vv[5][8];
#pragma unroll
  for (int c = 0; c < 5; ++c)
#pragma unroll
    for (int j = 0; j < 8; ++j) {
      int kg = kbase + 32 * c + 8 * g + j;
      kg = kg < 0 ? 0 : (kg > SEQ - 1 ? SEQ - 1 : kg);
      vv[c][j] = *(const float2*)(vb + (size_t)kg * DIME + 32 * w + 2 * col);
    }

  // ---- zero P pad rows 144..159 (key slots beyond tile 8) ----
  P[144 + (tid >> 4)][tid & 15] = 0.f;

  // ---- S phase: per-tile QK^T, mask, per-tile softmax stats, stage P ----
  const float scale = 0.08838834764831845f;  // 128^-0.5
  auto process = [&](int t, const float4 (&raw)[8]) {
    f32x4 acc = {0.f, 0.f, 0.f, 0.f};
#pragma unroll
    for (int kc = 0; kc < 4; ++kc)
      acc = __builtin_amdgcn_mfma_f32_16x16x32_bf16(
          pack8(raw[2 * kc], raw[2 * kc + 1]), qf[kc], acc, 0, 0, 0);
    float sc[4];
    float m = NEG_INF;
#pragma unroll
    for (int r = 0; r < 4; ++r) {
      const int kg = kbase + 16 * t + 4 * g + r;
      const int qg = qs + col;
      const bool valid = (kg >= 0) && (kg >= qg - 128) && (kg <= qg);
      sc[r] = valid ? acc[r] * scale : NEG_INF;
      m = fmaxf(m, sc[r]);
    }
    m = fmaxf(m, __shfl_xor(m, 16));
    m = fmaxf(m, __shfl_xor(m, 32));
    float s = 0.f;
#pragma unroll
    for (int r = 0; r < 4; ++r) { sc[r] = __expf(sc[r] - m); s += sc[r]; }
    s += __shfl_xor(s, 16);
    s += __shfl_xor(s, 32);
    if (g == 0) { mW[t][col] = m; sW[t][col] = s; }
#pragma unroll
    for (int r = 0; r < 4; ++r) P[16 * t + 4 * g + r][col] = sc[r];
  };
  process(2 * w, kraw[0]);
  process(2 * w + 1, kraw[1]);
  if (w == 0) process(8, kraw[2]);

  __syncthreads();

  // ---- combine: scaleW[t][q] = exp(m_t - M) / S_total  (folds normalize) ----
  if (tid < 160) {
    const int t = tid >> 4, qq = tid & 15;
    if (t == 9) {
      scaleW[9][qq] = 0.f;
    } else {
      float M = mW[0][qq];
#pragma unroll
      for (int t2 = 1; t2 < 9; ++t2) M = fmaxf(M, mW[t2][qq]);
      float St = 0.f;
#pragma unroll
      for (int t2 = 0; t2 < 9; ++t2) St += sW[t2][qq] * __expf(mW[t2][qq] - M);
      scaleW[t][qq] = __expf(mW[t][qq] - M) / St;
    }
  }
  __syncthreads();

  // ---- PV: contract all 160 key slots; V already in registers ----
  f32x4 o0 = {0.f, 0.f, 0.f, 0.f}, o1 = {0.f, 0.f, 0.f, 0.f};
#pragma unroll
  for (int c = 0; c < 5; ++c) {
    const float sw = scaleW[2 * c + (g >> 1)][col];  // t = (32c+8g+j)>>4, j<8
    bf16x8 pa, b0, b1;
#pragma unroll
    for (int j = 0; j < 8; ++j) {
      pa[j] = f2b(P[32 * c + 8 * g + j][col] * sw);  // A: row=q(col), k=key
      b0[j] = f2b(vv[c][j].x);                       // B: k=key, col->dim 2n
      b1[j] = f2b(vv[c][j].y);                       //            dim 2n+1
    }
    o0 = __builtin_amdgcn_mfma_f32_16x16x32_bf16(pa, b0, o0, 0, 0, 0);
    o1 = __builtin_amdgcn_mfma_f32_16x16x32_bf16(pa, b1, o1, 0, 0, 0);
  }

  // ---- store: C row = q = 4g+r, col -> dims 32w + 2col + {0,1} ----
#pragma unroll
  for (int r = 0; r < 4; ++r) {
    const int qrow = 4 * g + r;
    float2 val = {o0[r], o1[r]};
    *(float2*)&out[(size_t)(b * SEQ + qs + qrow) * DIME + 32 * w + 2 * col] = val;
  }
}

extern "C" void kernel_launch(void* const* d_in, const int* in_sizes, int n_in,
                              void* d_out, int out_size, void* d_ws, size_t ws_size,
                              hipStream_t stream) {
  const float* q = (const float*)d_in[0];
  const float* k = (const float*)d_in[1];
  const float* v = (const float*)d_in[2];
  float* out = (float*)d_out;
  // 2 batches x 128 q-tiles of 16 queries = 256 blocks, 4 waves each
  dim3 grid(256), block(256);
  swa_kernel<<<grid, block, 0, stream>>>(q, k, v, out);
}